// Round 1
// 378.663 us; speedup vs baseline: 1.0912x; 1.0912x over previous
//
#include <hip/hip_runtime.h>
#include <hip/hip_bf16.h>
#include <cstdint>
#include <type_traits>

typedef __attribute__((ext_vector_type(8))) short short8;
typedef __attribute__((ext_vector_type(4))) float floatx4;

constexpr int S_LEN = 2048;
constexpr float ATTN_SCALE = 0.08838834764831845f;  // 128^-0.5
constexpr float LOG2E = 1.4426950408889634f;
constexpr float CP = ATTN_SCALE * LOG2E;            // fold scale into exp2 arg

// ---------------------------------------------------------------- async G->LDS
__device__ __forceinline__ void gl_lds16(const void* gp, void* lp) {
  __builtin_amdgcn_global_load_lds(
      (__attribute__((address_space(1))) void*)(uintptr_t)gp,
      (__attribute__((address_space(3))) void*)lp,
      16, 0, 0);
}

// ------------------------------------------------ 16-lane max via DPP row_ror
__device__ __forceinline__ float rowmax16(float x) {
  union { float f; int i; } a, b;
  a.f = x;
  b.i = __builtin_amdgcn_update_dpp(0, a.i, 0x121, 0xF, 0xF, true);  // ror:1
  x = fmaxf(x, b.f); a.f = x;
  b.i = __builtin_amdgcn_update_dpp(0, a.i, 0x122, 0xF, 0xF, true);  // ror:2
  x = fmaxf(x, b.f); a.f = x;
  b.i = __builtin_amdgcn_update_dpp(0, a.i, 0x124, 0xF, 0xF, true);  // ror:4
  x = fmaxf(x, b.f); a.f = x;
  b.i = __builtin_amdgcn_update_dpp(0, a.i, 0x128, 0xF, 0xF, true);  // ror:8
  return fmaxf(x, b.f);
}

// --------------------------------------------------------------------- RoPE
__device__ __forceinline__ void rope8(short8 x0, short8 x1, const float* ca,
                                      const float* sa, const float* cb,
                                      const float* sb, short8& y0, short8& y1) {
#pragma unroll
  for (int e = 0; e < 8; ++e) {
    union { short s; __hip_bfloat16 h; } u0, u1, w0, w1;
    u0.s = x0[e]; u1.s = x1[e];
    float f0 = __bfloat162float(u0.h), f1 = __bfloat162float(u1.h);
    int j = e >> 1;
    w0.h = __float2bfloat16(f0 * ca[j] - f1 * sa[j]);
    w1.h = __float2bfloat16(f1 * cb[j] + f0 * sb[j]);
    y0[e] = w0.s; y1[e] = w1.s;
  }
}

// ------------------------------------------------------------- fused prologue
__device__ __forceinline__ void tr32(const float* __restrict__ src,
                                     __hip_bfloat16* __restrict__ dst,
                                     int blk, int nblk_x, int N, int tid,
                                     float (*tile)[33]) {
  int n0 = (blk % nblk_x) * 32, k0 = (blk / nblk_x) * 32;
  int tx = tid & 31, ty = tid >> 5;   // (32, 8)
#pragma unroll
  for (int i = ty; i < 32; i += 8)
    tile[i][tx] = src[(size_t)(k0 + i) * N + n0 + tx];
  __syncthreads();
#pragma unroll
  for (int i = ty; i < 32; i += 8)
    dst[(size_t)(n0 + i) * 2048 + k0 + tx] = __float2bfloat16(tile[tx][i]);
}

__global__ void prep_kernel(const float* __restrict__ x,
                            const float* __restrict__ Wq,
                            const float* __restrict__ Wk,
                            const float* __restrict__ Wv,
                            const float* __restrict__ Wo,
                            __hip_bfloat16* __restrict__ xb,
                            __hip_bfloat16* __restrict__ wqkvt,
                            __hip_bfloat16* __restrict__ wot) {
  __shared__ float tile[32][33];
  int bx = blockIdx.x, tid = threadIdx.x;
  if (bx < 8192) {
    int i = bx * 256 + tid;           // 2097152 float4s exactly
    float4 f = reinterpret_cast<const float4*>(x)[i];
    union { unsigned long long u64; __hip_bfloat16 h[4]; } u;
    u.h[0] = __float2bfloat16(f.x);
    u.h[1] = __float2bfloat16(f.y);
    u.h[2] = __float2bfloat16(f.z);
    u.h[3] = __float2bfloat16(f.w);
    reinterpret_cast<unsigned long long*>(xb)[i] = u.u64;
  } else if (bx < 12288) {
    tr32(Wq, wqkvt, bx - 8192, 64, 2048, tid, tile);
  } else if (bx < 13312) {
    tr32(Wk, wqkvt + 2048 * 2048, bx - 12288, 16, 512, tid, tile);
  } else if (bx < 14336) {
    tr32(Wv, wqkvt + 2560 * 2048, bx - 13312, 16, 512, tid, tile);
  } else {
    tr32(Wo, wot, bx - 14336, 64, 2048, tid, tile);
  }
}

// ===================================================================
// 256x256-tile 8-phase GEMM core (T3+T4+T5). BK=64, 8 waves (2M x 4N),
// 128 KiB double-buffered LDS (chunk-transposed [kchunk][row][8] layout).
// Per K-tile: 4 phases x {ds_read subtile; stage 1 half-tile; barrier;
// lgkmcnt(0); setprio(1); 16 MFMA; setprio(0); barrier}. vmcnt(4) once per
// K-tile (2 half-tiles stay in flight across barriers).
// Staging ledger (race-free):
//   phase0: A(t+1)lo -> buf[~p] A  (A[~p] last read tile t-1 ph3, drained)
//   phase1: A(t+1)hi -> buf[~p] A
//   phase2: B(t+2)lo -> buf[p] B   (B[p] read only in ph0, drained)
//   phase3: B(t+2)hi -> buf[p] B
// vmcnt(4) at ph3 => everything through A(t+1)hi landed => tile t+1 resident.
// ===================================================================
__device__ __forceinline__ void gemm256_core(
    const __hip_bfloat16* __restrict__ Ab,   // A + m0*K, row-major [.][K]
    const __hip_bfloat16* __restrict__ Bb,   // Bt + n0*K, row-major [.][K]
    const int K, __hip_bfloat16* lds, floatx4 (&acc)[8][4]) {
  const int tid = threadIdx.x;
  const int wave = tid >> 6, lane = tid & 63;
  const int quad = lane >> 4, l15 = lane & 15;
  const int wm = wave >> 2, wn = wave & 3;
  const int nt = K >> 6;
  const int u2 = wave * 2;

  auto stA = [&](int tt, int h) {
    __hip_bfloat16* dst = lds + (tt & 1) * 32768;
    const int k0 = tt << 6;
#pragma unroll
    for (int j = 0; j < 2; ++j) {
      const int kc = (u2 + j) >> 1, rb = (u2 + j) & 1;
      gl_lds16(Ab + (size_t)(h * 128 + rb * 64 + lane) * K + k0 + kc * 8,
               dst + (kc * 256 + h * 128 + rb * 64) * 8);
    }
  };
  auto stB = [&](int tt, int h) {
    __hip_bfloat16* dst = lds + (tt & 1) * 32768 + 16384;
    const int k0 = tt << 6;
#pragma unroll
    for (int j = 0; j < 2; ++j) {
      const int kc = (u2 + j) >> 1, rb = (u2 + j) & 1;
      gl_lds16(Bb + (size_t)(h * 128 + rb * 64 + lane) * K + k0 + kc * 8,
               dst + (kc * 256 + h * 128 + rb * 64) * 8);
    }
  };

  // prologue: tile0 fully + tile1 B halves (A1 staged in tile0 ph0/ph1)
  stA(0, 0); stA(0, 1); stB(0, 0); stB(0, 1);
  if (nt > 1) { stB(1, 0); stB(1, 1); }
  asm volatile("s_waitcnt vmcnt(4)" ::: "memory");   // tile0's 8 loads landed
  __builtin_amdgcn_s_barrier();

  const int abase = (quad * 256 + wm * 128 + l15) * 8;
  const int bbase = (quad * 256 + wn * 64 + l15) * 8;

#pragma unroll 2
  for (int t = 0; t < nt; ++t) {
    const __hip_bfloat16* Al = lds + (t & 1) * 32768;
    const __hip_bfloat16* Bl = Al + 16384;
    short8 b[2][4];
#pragma unroll
    for (int q = 0; q < 4; ++q) {
      short8 a[2][2];
#pragma unroll
      for (int kk = 0; kk < 2; ++kk) {
        if (q == 0) {
#pragma unroll
          for (int ni = 0; ni < 4; ++ni)
            b[kk][ni] = *(const short8*)&Bl[kk * 8192 + bbase + ni * 128];
        }
#pragma unroll
        for (int mi = 0; mi < 2; ++mi)
          a[kk][mi] = *(const short8*)&Al[kk * 8192 + abase + (2 * q + mi) * 128];
      }
      if (q == 0)      { if (t + 1 < nt) stA(t + 1, 0); }
      else if (q == 1) { if (t + 1 < nt) stA(t + 1, 1); }
      else if (q == 2) { if (t + 2 < nt) stB(t + 2, 0); }
      else             { if (t + 2 < nt) stB(t + 2, 1); }
      __builtin_amdgcn_s_barrier();
      asm volatile("s_waitcnt lgkmcnt(0)" ::: "memory");
      __builtin_amdgcn_sched_barrier(0);    // rule #18: pin reads above MFMAs
      __builtin_amdgcn_s_setprio(1);
#pragma unroll
      for (int kk = 0; kk < 2; ++kk)
#pragma unroll
        for (int mi = 0; mi < 2; ++mi)
#pragma unroll
          for (int ni = 0; ni < 4; ++ni)
            acc[2 * q + mi][ni] = __builtin_amdgcn_mfma_f32_16x16x32_bf16(
                a[kk][mi], b[kk][ni], acc[2 * q + mi][ni], 0, 0, 0);
      __builtin_amdgcn_s_setprio(0);
      if (q == 3) {
        if (t + 2 < nt) asm volatile("s_waitcnt vmcnt(4)" ::: "memory");
        else            asm volatile("s_waitcnt vmcnt(0)" ::: "memory");
      }
      __builtin_amdgcn_s_barrier();
    }
  }
  asm volatile("" ::: "memory");   // fence before LDS reuse in epilogue
}

// ------------------------------------------------------------ QKV GEMM (fused)
// C = xb[4096][2048] @ wqkvt[3072][2048]^T, 256x256 tiles, grid (12,16).
// n-tiles 0..7 = Q (2 heads each), 8..9 = K (2 kv-heads each), 10..11 = V.
// Epilogue: C-tile -> 128 KiB LDS (bf16), then region writes identical in
// layout to the previous kernel (attn_kernel consumes unchanged formats).
__global__ __launch_bounds__(512, 2) void qkv_gemm_kernel(
    const __hip_bfloat16* __restrict__ A,
    const __hip_bfloat16* __restrict__ Bt,
    __hip_bfloat16* __restrict__ qbuf,
    __hip_bfloat16* __restrict__ kbuf,
    __hip_bfloat16* __restrict__ vbuf,
    const float* __restrict__ cosb,
    const float* __restrict__ sinb) {
  constexpr int K = 2048;
  __shared__ __align__(16) __hip_bfloat16 lds[65536];  // 128 KiB
  const int tid = threadIdx.x;
  const int m0 = blockIdx.y * 256, n0 = blockIdx.x * 256;

  floatx4 acc[8][4] = {};
  gemm256_core(A + (size_t)m0 * K, Bt + (size_t)n0 * K, K, lds, acc);

  const int wave = tid >> 6, lane = tid & 63;
  const int quad = lane >> 4, l15 = lane & 15;
  const int wm = wave >> 2, wn = wave & 3;
  const bool isv = (n0 >= 2560);
  short* lds2 = (short*)lds;                       // [256][256] bf16 = 128 KB
#pragma unroll
  for (int mi = 0; mi < 8; ++mi)
#pragma unroll
    for (int ni = 0; ni < 4; ++ni)
#pragma unroll
      for (int r = 0; r < 4; ++r) {
        int row = wm * 128 + mi * 16 + quad * 4 + r;  // C/D: row = quad*4+reg
        int col = wn * 64 + ni * 16 + l15;            //      col = lane&15
        union { short s; __hip_bfloat16 h; } u;
        u.h = __float2bfloat16(acc[mi][ni][r]);
        if (isv) lds2[col * 256 + row] = u.s;         // V stored transposed
        else     lds2[row * 256 + col] = u.s;
      }
  __syncthreads();

  const int c16 = tid & 15, hh = c16 >> 3, c8 = c16 & 7;
  const int rid = tid >> 4, d0 = c8 * 8;
  if (n0 < 2048) {
    // ---- Q: rope + row-major coalesced write (2 heads per tile)
#pragma unroll
    for (int j = 0; j < 8; ++j) {
      int rr = rid + 32 * j;
      int rowg = m0 + rr;
      int s = rowg & (S_LEN - 1);
      float ca[4], sa[4], cb[4], sb[4];
      *(float4*)ca = *(const float4*)&cosb[s * 64 + c8 * 4];
      *(float4*)sa = *(const float4*)&sinb[s * 64 + c8 * 4];
      *(float4*)cb = *(const float4*)&cosb[s * 64 + 32 + c8 * 4];
      *(float4*)sb = *(const float4*)&sinb[s * 64 + 32 + c8 * 4];
      short8 x0 = *(const short8*)&lds2[rr * 256 + hh * 128 + d0];
      short8 x1 = *(const short8*)&lds2[rr * 256 + hh * 128 + 64 + d0];
      short8 y0, y1;
      rope8(x0, x1, ca, sa, cb, sb, y0, y1);
      *(short8*)(qbuf + (size_t)rowg * 2048 + n0 + hh * 128 + d0) = y0;
      *(short8*)(qbuf + (size_t)rowg * 2048 + n0 + hh * 128 + 64 + d0) = y1;
    }
  } else if (!isv) {
    // ---- K: rope + chunk-transposed tile write (2 kv-heads per tile)
    const int kvh = ((n0 - 2048) >> 7) + hh;
#pragma unroll
    for (int j = 0; j < 8; ++j) {
      int rr = rid + 32 * j;
      int rowg = m0 + rr;
      int s = rowg & (S_LEN - 1), bb = rowg >> 11;
      int kv = s & 63;
      size_t tb = ((size_t)(bb * 4 + kvh) * 32 + (s >> 6)) * 8192;
      float ca[4], sa[4], cb[4], sb[4];
      *(float4*)ca = *(const float4*)&cosb[s * 64 + c8 * 4];
      *(float4*)sa = *(const float4*)&sinb[s * 64 + c8 * 4];
      *(float4*)cb = *(const float4*)&cosb[s * 64 + 32 + c8 * 4];
      *(float4*)sb = *(const float4*)&sinb[s * 64 + 32 + c8 * 4];
      short8 x0 = *(const short8*)&lds2[rr * 256 + hh * 128 + d0];
      short8 x1 = *(const short8*)&lds2[rr * 256 + hh * 128 + 64 + d0];
      short8 y0, y1;
      rope8(x0, x1, ca, sa, cb, sb, y0, y1);
      *(short8*)(kbuf + tb + (size_t)c8 * 512 + kv * 8) = y0;
      *(short8*)(kbuf + tb + (size_t)(8 + c8) * 512 + kv * 8) = y1;
    }
  } else {
    // ---- V: transposed XOR-swizzled tile write (2 kv-heads, 4 kv-tiles)
    const int kvh = ((n0 - 2560) >> 7) + hh;
    const int bb = m0 >> 11;
    const int kt0 = (m0 & (S_LEN - 1)) >> 6;
    const int kv0 = c8 * 8;
#pragma unroll
    for (int j = 0; j < 4; ++j) {
      int d = rid + 32 * j;            // 0..127 within head
      int cxor = (d & 7) << 3;
#pragma unroll
      for (int half = 0; half < 4; ++half) {
        short8 vv = *(const short8*)&lds2[(hh * 128 + d) * 256 + half * 64 + kv0];
        size_t tb = ((size_t)(bb * 4 + kvh) * 32 + kt0 + half) * 8192;
        *(short8*)(vbuf + tb + d * 64 + (kv0 ^ cxor)) = vv;
      }
    }
  }
}

// --------------------------------------------------------------- AO GEMM
__global__ __launch_bounds__(512, 2) void gemm_bt_f32_kernel(
    const __hip_bfloat16* __restrict__ A,
    const __hip_bfloat16* __restrict__ Bt,
    float* __restrict__ C, int N, int K) {
  __shared__ __align__(16) __hip_bfloat16 lds[65536];  // 128 KiB
  const int tid = threadIdx.x;
  const int m0 = blockIdx.y * 256, n0 = blockIdx.x * 256;

  floatx4 acc[8][4] = {};
  gemm256_core(A + (size_t)m0 * K, Bt + (size_t)n0 * K, K, lds, acc);

  const int wave = tid >> 6, lane = tid & 63;
  const int quad = lane >> 4, l15 = lane & 15;
  const int wm = wave >> 2, wn = wave & 3;
#pragma unroll
  for (int mi = 0; mi < 8; ++mi)
#pragma unroll
    for (int ni = 0; ni < 4; ++ni)
#pragma unroll
      for (int r = 0; r < 4; ++r) {
        int row = m0 + wm * 128 + mi * 16 + quad * 4 + r;
        int col = n0 + wn * 64 + ni * 16 + l15;
        C[(size_t)row * N + col] = acc[mi][ni][r];
      }
}

// ---------------------------------------------------------------- attention
__global__ __launch_bounds__(256, 2) void attn_kernel(
    const __hip_bfloat16* __restrict__ qbuf,   // [4096][2048]
    const __hip_bfloat16* __restrict__ kbuf,   // tiles
    const __hip_bfloat16* __restrict__ vbuf,   // tiles
    __hip_bfloat16* __restrict__ aout) {       // [4096][2048]
  const int qt = (blockIdx.y & 16) ? blockIdx.x : (15 - blockIdx.x);
  const int bh = blockIdx.y;
  const int b = bh >> 4, h = bh & 15;
  const int kvh = h >> 2;

  __shared__ __align__(16) __hip_bfloat16 Kbuf[2][8192];      // 2 x 16 KB
  __shared__ __align__(16) __hip_bfloat16 Vbuf[2][8192];      // 2 x 16 KB
  __shared__ __align__(16) __hip_bfloat16 Plds[4 * 16 * 72];  // 9 KB

  const int tid = threadIdx.x;
  const int wave = tid >> 6, lane = tid & 63;
  const int quad = lane >> 4, l15 = lane & 15;

  short8 qfrag[2][4];
#pragma unroll
  for (int rs = 0; rs < 2; ++rs)
#pragma unroll
    for (int kc = 0; kc < 4; ++kc)
      qfrag[rs][kc] = *(const short8*)(qbuf +
          (size_t)(b * S_LEN + qt * 128 + rs * 64 + wave * 16 + l15) * 2048 +
          h * 128 + kc * 32 + quad * 8);

  const __hip_bfloat16* ktiles = kbuf + (size_t)(b * 4 + kvh) * 32 * 8192;
  const __hip_bfloat16* vtiles = vbuf + (size_t)(b * 4 + kvh) * 32 * 8192;
  const int nt = 2 * qt + 2;

#pragma unroll
  for (int j = 0; j < 4; ++j) {
    int c = tid + 256 * j;
    gl_lds16(ktiles + c * 8, &Kbuf[0][c * 8]);
    gl_lds16(vtiles + c * 8, &Vbuf[0][c * 8]);
  }

  float m_r[2][4];
  floatx4 o[2][8] = {};
  floatx4 o_l[2] = {};
#pragma unroll
  for (int rs = 0; rs < 2; ++rs)
#pragma unroll
    for (int r = 0; r < 4; ++r) m_r[rs][r] = -1e30f;

  short8 onesb;
#pragma unroll
  for (int e = 0; e < 8; ++e) onesb[e] = (short)0x3F80;  // bf16 1.0

  __hip_bfloat16* pw = &Plds[wave * 16 * 72];

  for (int kt = 0; kt < nt; ++kt) {
    const int cur = kt & 1;
    __syncthreads();   // K(kt)/V(kt) DMA drained & visible

    if (kt + 1 < nt) {
      const __hip_bfloat16* kb = ktiles + (size_t)(kt + 1) * 8192;
      const __hip_bfloat16* vb = vtiles + (size_t)(kt + 1) * 8192;
#pragma unroll
      for (int j = 0; j < 4; ++j) {
        int c = tid + 256 * j;
        gl_lds16(kb + c * 8, &Kbuf[1 - cur][c * 8]);
        gl_lds16(vb + c * 8, &Vbuf[1 - cur][c * 8]);
      }
    }

    // S = Q K^T for both rowsets (K frags loaded once, used twice)
    floatx4 sc[2][4] = {};
#pragma unroll
    for (int ni = 0; ni < 4; ++ni)
#pragma unroll
      for (int kc = 0; kc < 4; ++kc) {
        short8 bf = *(const short8*)&Kbuf[cur][((kc * 4 + quad) * 64 + ni * 16 + l15) * 8];
        sc[0][ni] = __builtin_amdgcn_mfma_f32_16x16x32_bf16(qfrag[0][kc], bf, sc[0][ni], 0, 0, 0);
        sc[1][ni] = __builtin_amdgcn_mfma_f32_16x16x32_bf16(qfrag[1][kc], bf, sc[1][ni], 0, 0, 0);
      }

    short8 pa[2][2];
#pragma unroll
    for (int rs = 0; rs < 2; ++rs) {
      const int qt64 = 2 * qt + rs;
      if (kt >= qt64) {   // diagonal or beyond: causal mask (all-masked => p=0)
        const int qrow = qt * 128 + rs * 64 + wave * 16 + quad * 4;
#pragma unroll
        for (int ni = 0; ni < 4; ++ni) {
          int kvcol = kt * 64 + ni * 16 + l15;
#pragma unroll
          for (int r = 0; r < 4; ++r)
            if (kvcol > qrow + r) sc[rs][ni][r] = -1e30f;
        }
      }

      // online softmax (raw-unit max; scale folded into exp2 args via CP)
      float alpha[4];
#pragma unroll
      for (int r = 0; r < 4; ++r) {
        float v = fmaxf(fmaxf(sc[rs][0][r], sc[rs][1][r]),
                        fmaxf(sc[rs][2][r], sc[rs][3][r]));
        v = rowmax16(v);
        float mnew = fmaxf(m_r[rs][r], v);
        alpha[r] = exp2f((m_r[rs][r] - mnew) * CP);
        m_r[rs][r] = mnew;
        float mc = mnew * CP;
#pragma unroll
        for (int ni = 0; ni < 4; ++ni) {
          float p = exp2f(sc[rs][ni][r] * CP - mc);
          pw[(quad * 4 + r) * 72 + ni * 16 + l15] = __float2bfloat16(p);
        }
      }

#pragma unroll
      for (int kk2 = 0; kk2 < 2; ++kk2)
        pa[rs][kk2] = *(const short8*)&pw[l15 * 72 + kk2 * 32 + quad * 8];

#pragma unroll
      for (int nc = 0; nc < 8; ++nc)
#pragma unroll
        for (int r = 0; r < 4; ++r) o[rs][nc][r] *= alpha[r];
#pragma unroll
      for (int r = 0; r < 4; ++r) o_l[rs][r] *= alpha[r];
    }

    // fused PV: each V fragment loaded once, used by both rowsets
#pragma unroll
    for (int kk2 = 0; kk2 < 2; ++kk2) {
#pragma unroll
      for (int nc = 0; nc < 8; ++nc) {
        int d = nc * 16 + l15;
        int swcol = (kk2 * 32 + quad * 8) ^ ((d & 7) << 3);
        short8 vv = *(const short8*)&Vbuf[cur][d * 64 + swcol];
        o[0][nc] = __builtin_amdgcn_mfma_f32_16x16x32_bf16(pa[0][kk2], vv, o[0][nc], 0, 0, 0);
        o[1][nc] = __builtin_amdgcn_mfma_f32_16x16x32_bf16(pa[1][kk2], vv, o[1][nc], 0, 0, 0);
      }
      o_l[0] = __builtin_amdgcn_mfma_f32_16x16x32_bf16(pa[0][kk2], onesb, o_l[0], 0, 0, 0);
      o_l[1] = __builtin_amdgcn_mfma_f32_16x16x32_bf16(pa[1][kk2], onesb, o_l[1], 0, 0, 0);
    }
  }

#pragma unroll
  for (int rs = 0; rs < 2; ++rs) {
    float inv[4];
#pragma unroll
    for (int r = 0; r < 4; ++r) inv[r] = 1.0f / o_l[rs][r];
    const size_t orow0 = (size_t)(b * S_LEN + qt * 128 + rs * 64 + wave * 16 + quad * 4);
#pragma unroll
    for (int nc = 0; nc < 8; ++nc)
#pragma unroll
      for (int r = 0; r < 4; ++r)
        aout[(orow0 + r) * 2048 + h * 128 + nc * 16 + l15] =
            __float2bfloat16(o[rs][nc][r] * inv[r]);
  }
}

// -------------------------------------------------------------------- launch
extern "C" void kernel_launch(void* const* d_in, const int* in_sizes, int n_in,
                              void* d_out, int out_size, void* d_ws, size_t ws_size,
                              hipStream_t stream) {
  const float* x    = (const float*)d_in[0];
  const float* cosb = (const float*)d_in[1];
  const float* sinb = (const float*)d_in[2];
  // d_in[3] = mask (causal, analytic)
  const float* Wq = (const float*)d_in[4];
  const float* Wk = (const float*)d_in[5];
  const float* Wv = (const float*)d_in[6];
  const float* Wo = (const float*)d_in[7];
  float* out = (float*)d_out;

  char* ws = (char*)d_ws;
  __hip_bfloat16* xb    = (__hip_bfloat16*)(ws);                 // 16 MB
  __hip_bfloat16* wqkvt = (__hip_bfloat16*)(ws + (16u << 20));   // 12 MB [3072][2048]
  __hip_bfloat16* wot   = (__hip_bfloat16*)(ws + (28u << 20));   // 8 MB  [2048][2048]
  __hip_bfloat16* qbuf  = (__hip_bfloat16*)(ws + (36u << 20));   // 16 MB [4096][2048]
  __hip_bfloat16* kbuf  = (__hip_bfloat16*)(ws + (52u << 20));   // 4 MB  tiles
  __hip_bfloat16* vbuf  = (__hip_bfloat16*)(ws + (56u << 20));   // 4 MB  tiles
  __hip_bfloat16* aout  = (__hip_bfloat16*)(ws + (60u << 20));   // 16 MB [4096][2048]

  prep_kernel<<<18432, 256, 0, stream>>>(x, Wq, Wk, Wv, Wo, xb, wqkvt, wot);
  qkv_gemm_kernel<<<dim3(12, 16), 512, 0, stream>>>(xb, wqkvt, qbuf, kbuf, vbuf, cosb, sinb);
  attn_kernel<<<dim3(16, 32), 256, 0, stream>>>(qbuf, kbuf, vbuf, aout);
  gemm_bt_f32_kernel<<<dim3(8, 16), 512, 0, stream>>>(aout, wot, out, 2048, 2048);
}

// Round 2
// 366.688 us; speedup vs baseline: 1.1269x; 1.0327x over previous
//
#include <hip/hip_runtime.h>
#include <hip/hip_bf16.h>
#include <cstdint>
#include <type_traits>

typedef __attribute__((ext_vector_type(8))) short short8;
typedef __attribute__((ext_vector_type(4))) float floatx4;

constexpr int S_LEN = 2048;
constexpr float ATTN_SCALE = 0.08838834764831845f;  // 128^-0.5
constexpr float LOG2E = 1.4426950408889634f;
constexpr float CP = ATTN_SCALE * LOG2E;            // fold scale into exp2 arg
constexpr float THRR = 5.0f / CP;                   // defer-max threshold (raw units)

// ---------------------------------------------------------------- async G->LDS
__device__ __forceinline__ void gl_lds16(const void* gp, void* lp) {
  __builtin_amdgcn_global_load_lds(
      (__attribute__((address_space(1))) void*)(uintptr_t)gp,
      (__attribute__((address_space(3))) void*)lp,
      16, 0, 0);
}

// --------------------------------------------------------------------- RoPE
__device__ __forceinline__ void rope8(short8 x0, short8 x1, const float* ca,
                                      const float* sa, const float* cb,
                                      const float* sb, short8& y0, short8& y1) {
#pragma unroll
  for (int e = 0; e < 8; ++e) {
    union { short s; __hip_bfloat16 h; } u0, u1, w0, w1;
    u0.s = x0[e]; u1.s = x1[e];
    float f0 = __bfloat162float(u0.h), f1 = __bfloat162float(u1.h);
    int j = e >> 1;
    w0.h = __float2bfloat16(f0 * ca[j] - f1 * sa[j]);
    w1.h = __float2bfloat16(f1 * cb[j] + f0 * sb[j]);
    y0[e] = w0.s; y1[e] = w1.s;
  }
}

// ------------------------------------------------------------- fused prologue
__device__ __forceinline__ void tr32(const float* __restrict__ src,
                                     __hip_bfloat16* __restrict__ dst,
                                     int blk, int nblk_x, int N, int tid,
                                     float (*tile)[33]) {
  int n0 = (blk % nblk_x) * 32, k0 = (blk / nblk_x) * 32;
  int tx = tid & 31, ty = tid >> 5;   // (32, 8)
#pragma unroll
  for (int i = ty; i < 32; i += 8)
    tile[i][tx] = src[(size_t)(k0 + i) * N + n0 + tx];
  __syncthreads();
#pragma unroll
  for (int i = ty; i < 32; i += 8)
    dst[(size_t)(n0 + i) * 2048 + k0 + tx] = __float2bfloat16(tile[tx][i]);
}

__global__ void prep_kernel(const float* __restrict__ x,
                            const float* __restrict__ Wq,
                            const float* __restrict__ Wk,
                            const float* __restrict__ Wv,
                            const float* __restrict__ Wo,
                            __hip_bfloat16* __restrict__ xb,
                            __hip_bfloat16* __restrict__ wqkvt,
                            __hip_bfloat16* __restrict__ wot) {
  __shared__ float tile[32][33];
  int bx = blockIdx.x, tid = threadIdx.x;
  if (bx < 8192) {
    int i = bx * 256 + tid;           // 2097152 float4s exactly
    float4 f = reinterpret_cast<const float4*>(x)[i];
    union { unsigned long long u64; __hip_bfloat16 h[4]; } u;
    u.h[0] = __float2bfloat16(f.x);
    u.h[1] = __float2bfloat16(f.y);
    u.h[2] = __float2bfloat16(f.z);
    u.h[3] = __float2bfloat16(f.w);
    reinterpret_cast<unsigned long long*>(xb)[i] = u.u64;
  } else if (bx < 12288) {
    tr32(Wq, wqkvt, bx - 8192, 64, 2048, tid, tile);
  } else if (bx < 13312) {
    tr32(Wk, wqkvt + 2048 * 2048, bx - 12288, 16, 512, tid, tile);
  } else if (bx < 14336) {
    tr32(Wv, wqkvt + 2560 * 2048, bx - 13312, 16, 512, tid, tile);
  } else {
    tr32(Wo, wot, bx - 14336, 64, 2048, tid, tile);
  }
}

// ===================================================================
// 256x256-tile 8-phase GEMM core (unchanged, proven). BK=64, 8 waves (2Mx4N),
// 128 KiB dbuf LDS, counted vmcnt(4), setprio around MFMA clusters.
// ===================================================================
__device__ __forceinline__ void gemm256_core(
    const __hip_bfloat16* __restrict__ Ab,   // A + m0*K, row-major [.][K]
    const __hip_bfloat16* __restrict__ Bb,   // Bt + n0*K, row-major [.][K]
    const int K, __hip_bfloat16* lds, floatx4 (&acc)[8][4]) {
  const int tid = threadIdx.x;
  const int wave = tid >> 6, lane = tid & 63;
  const int quad = lane >> 4, l15 = lane & 15;
  const int wm = wave >> 2, wn = wave & 3;
  const int nt = K >> 6;
  const int u2 = wave * 2;

  auto stA = [&](int tt, int h) {
    __hip_bfloat16* dst = lds + (tt & 1) * 32768;
    const int k0 = tt << 6;
#pragma unroll
    for (int j = 0; j < 2; ++j) {
      const int kc = (u2 + j) >> 1, rb = (u2 + j) & 1;
      gl_lds16(Ab + (size_t)(h * 128 + rb * 64 + lane) * K + k0 + kc * 8,
               dst + (kc * 256 + h * 128 + rb * 64) * 8);
    }
  };
  auto stB = [&](int tt, int h) {
    __hip_bfloat16* dst = lds + (tt & 1) * 32768 + 16384;
    const int k0 = tt << 6;
#pragma unroll
    for (int j = 0; j < 2; ++j) {
      const int kc = (u2 + j) >> 1, rb = (u2 + j) & 1;
      gl_lds16(Bb + (size_t)(h * 128 + rb * 64 + lane) * K + k0 + kc * 8,
               dst + (kc * 256 + h * 128 + rb * 64) * 8);
    }
  };

  // prologue: tile0 fully + tile1 B halves (A1 staged in tile0 ph0/ph1)
  stA(0, 0); stA(0, 1); stB(0, 0); stB(0, 1);
  if (nt > 1) { stB(1, 0); stB(1, 1); }
  asm volatile("s_waitcnt vmcnt(4)" ::: "memory");   // tile0's 8 loads landed
  __builtin_amdgcn_s_barrier();

  const int abase = (quad * 256 + wm * 128 + l15) * 8;
  const int bbase = (quad * 256 + wn * 64 + l15) * 8;

#pragma unroll 2
  for (int t = 0; t < nt; ++t) {
    const __hip_bfloat16* Al = lds + (t & 1) * 32768;
    const __hip_bfloat16* Bl = Al + 16384;
    short8 b[2][4];
#pragma unroll
    for (int q = 0; q < 4; ++q) {
      short8 a[2][2];
#pragma unroll
      for (int kk = 0; kk < 2; ++kk) {
        if (q == 0) {
#pragma unroll
          for (int ni = 0; ni < 4; ++ni)
            b[kk][ni] = *(const short8*)&Bl[kk * 8192 + bbase + ni * 128];
        }
#pragma unroll
        for (int mi = 0; mi < 2; ++mi)
          a[kk][mi] = *(const short8*)&Al[kk * 8192 + abase + (2 * q + mi) * 128];
      }
      if (q == 0)      { if (t + 1 < nt) stA(t + 1, 0); }
      else if (q == 1) { if (t + 1 < nt) stA(t + 1, 1); }
      else if (q == 2) { if (t + 2 < nt) stB(t + 2, 0); }
      else             { if (t + 2 < nt) stB(t + 2, 1); }
      __builtin_amdgcn_s_barrier();
      asm volatile("s_waitcnt lgkmcnt(0)" ::: "memory");
      __builtin_amdgcn_sched_barrier(0);    // rule #18: pin reads above MFMAs
      __builtin_amdgcn_s_setprio(1);
#pragma unroll
      for (int kk = 0; kk < 2; ++kk)
#pragma unroll
        for (int mi = 0; mi < 2; ++mi)
#pragma unroll
          for (int ni = 0; ni < 4; ++ni)
            acc[2 * q + mi][ni] = __builtin_amdgcn_mfma_f32_16x16x32_bf16(
                a[kk][mi], b[kk][ni], acc[2 * q + mi][ni], 0, 0, 0);
      __builtin_amdgcn_s_setprio(0);
      if (q == 3) {
        if (t + 2 < nt) asm volatile("s_waitcnt vmcnt(4)" ::: "memory");
        else            asm volatile("s_waitcnt vmcnt(0)" ::: "memory");
      }
      __builtin_amdgcn_s_barrier();
    }
  }
  asm volatile("" ::: "memory");   // fence before LDS reuse in epilogue
}

// ===================================================================
// 256x128-tile 2-phase GEMM core. 8 waves (4M x 2N), BK=64, 96 KiB dbuf LDS.
// Per K-tile 6 staging slots: A = 4 calls, B = 2. Ledger:
//   ph0: stage A(t+1)c0,c1 -> buf[~p]A  (A[~p] reads done at t-1 ph1 lgkm)
//   ph1: stage A(t+1)c2,c3 + B(t+2)c0,c1 -> buf[p]B (B[p] reads done ph0 lgkm)
//   vmcnt(2) at ph1 end => B(t+1)+A(t+1) (first 6 of 8 in flight) landed.
// ===================================================================
__device__ __forceinline__ void gemm_256x128_core(
    const __hip_bfloat16* __restrict__ Ab,
    const __hip_bfloat16* __restrict__ Bb,
    const int K, __hip_bfloat16* lds, floatx4 (&acc)[4][4]) {
  const int tid = threadIdx.x;
  const int wave = tid >> 6, lane = tid & 63;
  const int quad = lane >> 4, l15 = lane & 15;
  const int wm = wave >> 1, wn = wave & 1;
  const int nt = K >> 6;

  auto stA = [&](int tt, int c) {     // c in 0..3
    __hip_bfloat16* dst = lds + (tt & 1) * 24576;
    const int k0 = tt << 6;
    const int i = c * 8 + wave;       // 0..31: kc = i>>2, rowblk = i&3
    const int kc = i >> 2, rb = i & 3;
    gl_lds16(Ab + (size_t)(rb * 64 + lane) * K + k0 + kc * 8,
             dst + (kc * 256 + rb * 64) * 8);
  };
  auto stB = [&](int tt, int c) {     // c in 0..1
    __hip_bfloat16* dst = lds + (tt & 1) * 24576 + 16384;
    const int k0 = tt << 6;
    const int i = c * 8 + wave;       // 0..15: kc = i>>1, rowblk = i&1
    const int kc = i >> 1, rb = i & 1;
    gl_lds16(Bb + (size_t)(rb * 64 + lane) * K + k0 + kc * 8,
             dst + (kc * 128 + rb * 64) * 8);
  };

  stA(0, 0); stA(0, 1); stA(0, 2); stA(0, 3);
  stB(0, 0); stB(0, 1);
  if (nt > 1) {
    stB(1, 0); stB(1, 1);
    asm volatile("s_waitcnt vmcnt(2)" ::: "memory");
  } else {
    asm volatile("s_waitcnt vmcnt(0)" ::: "memory");
  }
  __builtin_amdgcn_s_barrier();

  const int abase = (quad * 256 + wm * 64 + l15) * 8;
  const int bbase = (quad * 128 + wn * 64 + l15) * 8;

#pragma unroll 2
  for (int t = 0; t < nt; ++t) {
    const __hip_bfloat16* Al = lds + (t & 1) * 24576;
    const __hip_bfloat16* Bl = Al + 16384;
    short8 b[2][4], a[2][2];
    // ---- phase 0: mi 0,1 (B frags read once per tile, reused in ph1)
#pragma unroll
    for (int kk = 0; kk < 2; ++kk) {
#pragma unroll
      for (int ni = 0; ni < 4; ++ni)
        b[kk][ni] = *(const short8*)&Bl[kk * 4096 + bbase + ni * 128];
#pragma unroll
      for (int mi = 0; mi < 2; ++mi)
        a[kk][mi] = *(const short8*)&Al[kk * 8192 + abase + mi * 128];
    }
    if (t + 1 < nt) { stA(t + 1, 0); stA(t + 1, 1); }
    __builtin_amdgcn_s_barrier();
    asm volatile("s_waitcnt lgkmcnt(0)" ::: "memory");
    __builtin_amdgcn_sched_barrier(0);
    __builtin_amdgcn_s_setprio(1);
#pragma unroll
    for (int kk = 0; kk < 2; ++kk)
#pragma unroll
      for (int mi = 0; mi < 2; ++mi)
#pragma unroll
        for (int ni = 0; ni < 4; ++ni)
          acc[mi][ni] = __builtin_amdgcn_mfma_f32_16x16x32_bf16(
              a[kk][mi], b[kk][ni], acc[mi][ni], 0, 0, 0);
    __builtin_amdgcn_s_setprio(0);
    __builtin_amdgcn_s_barrier();
    // ---- phase 1: mi 2,3
#pragma unroll
    for (int kk = 0; kk < 2; ++kk)
#pragma unroll
      for (int mi = 0; mi < 2; ++mi)
        a[kk][mi] = *(const short8*)&Al[kk * 8192 + abase + (2 + mi) * 128];
    if (t + 1 < nt) { stA(t + 1, 2); stA(t + 1, 3); }
    if (t + 2 < nt) { stB(t + 2, 0); stB(t + 2, 1); }
    __builtin_amdgcn_s_barrier();
    asm volatile("s_waitcnt lgkmcnt(0)" ::: "memory");
    __builtin_amdgcn_sched_barrier(0);
    __builtin_amdgcn_s_setprio(1);
#pragma unroll
    for (int kk = 0; kk < 2; ++kk)
#pragma unroll
      for (int mi = 0; mi < 2; ++mi)
#pragma unroll
        for (int ni = 0; ni < 4; ++ni)
          acc[2 + mi][ni] = __builtin_amdgcn_mfma_f32_16x16x32_bf16(
              a[kk][mi], b[kk][ni], acc[2 + mi][ni], 0, 0, 0);
    __builtin_amdgcn_s_setprio(0);
    if (t + 2 < nt) asm volatile("s_waitcnt vmcnt(2)" ::: "memory");
    else            asm volatile("s_waitcnt vmcnt(0)" ::: "memory");
    __builtin_amdgcn_s_barrier();
  }
  asm volatile("" ::: "memory");
}

// ------------------------------------------------------------ QKV GEMM (fused)
__global__ __launch_bounds__(512, 2) void qkv_gemm_kernel(
    const __hip_bfloat16* __restrict__ A,
    const __hip_bfloat16* __restrict__ Bt,
    __hip_bfloat16* __restrict__ qbuf,
    __hip_bfloat16* __restrict__ kbuf,
    __hip_bfloat16* __restrict__ vbuf,
    const float* __restrict__ cosb,
    const float* __restrict__ sinb) {
  constexpr int K = 2048;
  __shared__ __align__(16) __hip_bfloat16 lds[65536];  // 128 KiB
  const int tid = threadIdx.x;
  const int m0 = blockIdx.y * 256, n0 = blockIdx.x * 256;

  floatx4 acc[8][4] = {};
  gemm256_core(A + (size_t)m0 * K, Bt + (size_t)n0 * K, K, lds, acc);

  const int wave = tid >> 6, lane = tid & 63;
  const int quad = lane >> 4, l15 = lane & 15;
  const int wm = wave >> 2, wn = wave & 3;
  const bool isv = (n0 >= 2560);
  short* lds2 = (short*)lds;                       // [256][256] bf16 = 128 KB
#pragma unroll
  for (int mi = 0; mi < 8; ++mi)
#pragma unroll
    for (int ni = 0; ni < 4; ++ni)
#pragma unroll
      for (int r = 0; r < 4; ++r) {
        int row = wm * 128 + mi * 16 + quad * 4 + r;  // C/D: row = quad*4+reg
        int col = wn * 64 + ni * 16 + l15;            //      col = lane&15
        union { short s; __hip_bfloat16 h; } u;
        u.h = __float2bfloat16(acc[mi][ni][r]);
        if (isv) lds2[col * 256 + row] = u.s;         // V stored transposed
        else     lds2[row * 256 + col] = u.s;
      }
  __syncthreads();

  const int c16 = tid & 15, hh = c16 >> 3, c8 = c16 & 7;
  const int rid = tid >> 4, d0 = c8 * 8;
  if (n0 < 2048) {
    // ---- Q: rope + row-major coalesced write (2 heads per tile)
#pragma unroll
    for (int j = 0; j < 8; ++j) {
      int rr = rid + 32 * j;
      int rowg = m0 + rr;
      int s = rowg & (S_LEN - 1);
      float ca[4], sa[4], cb[4], sb[4];
      *(float4*)ca = *(const float4*)&cosb[s * 64 + c8 * 4];
      *(float4*)sa = *(const float4*)&sinb[s * 64 + c8 * 4];
      *(float4*)cb = *(const float4*)&cosb[s * 64 + 32 + c8 * 4];
      *(float4*)sb = *(const float4*)&sinb[s * 64 + 32 + c8 * 4];
      short8 x0 = *(const short8*)&lds2[rr * 256 + hh * 128 + d0];
      short8 x1 = *(const short8*)&lds2[rr * 256 + hh * 128 + 64 + d0];
      short8 y0, y1;
      rope8(x0, x1, ca, sa, cb, sb, y0, y1);
      *(short8*)(qbuf + (size_t)rowg * 2048 + n0 + hh * 128 + d0) = y0;
      *(short8*)(qbuf + (size_t)rowg * 2048 + n0 + hh * 128 + 64 + d0) = y1;
    }
  } else if (!isv) {
    // ---- K: rope + chunk-transposed tile write (2 kv-heads per tile)
    const int kvh = ((n0 - 2048) >> 7) + hh;
#pragma unroll
    for (int j = 0; j < 8; ++j) {
      int rr = rid + 32 * j;
      int rowg = m0 + rr;
      int s = rowg & (S_LEN - 1), bb = rowg >> 11;
      int kv = s & 63;
      size_t tb = ((size_t)(bb * 4 + kvh) * 32 + (s >> 6)) * 8192;
      float ca[4], sa[4], cb[4], sb[4];
      *(float4*)ca = *(const float4*)&cosb[s * 64 + c8 * 4];
      *(float4*)sa = *(const float4*)&sinb[s * 64 + c8 * 4];
      *(float4*)cb = *(const float4*)&cosb[s * 64 + 32 + c8 * 4];
      *(float4*)sb = *(const float4*)&sinb[s * 64 + 32 + c8 * 4];
      short8 x0 = *(const short8*)&lds2[rr * 256 + hh * 128 + d0];
      short8 x1 = *(const short8*)&lds2[rr * 256 + hh * 128 + 64 + d0];
      short8 y0, y1;
      rope8(x0, x1, ca, sa, cb, sb, y0, y1);
      *(short8*)(kbuf + tb + (size_t)c8 * 512 + kv * 8) = y0;
      *(short8*)(kbuf + tb + (size_t)(8 + c8) * 512 + kv * 8) = y1;
    }
  } else {
    // ---- V: transposed XOR-swizzled tile write (2 kv-heads, 4 kv-tiles)
    const int kvh = ((n0 - 2560) >> 7) + hh;
    const int bb = m0 >> 11;
    const int kt0 = (m0 & (S_LEN - 1)) >> 6;
    const int kv0 = c8 * 8;
#pragma unroll
    for (int j = 0; j < 4; ++j) {
      int d = rid + 32 * j;            // 0..127 within head
      int cxor = (d & 7) << 3;
#pragma unroll
      for (int half = 0; half < 4; ++half) {
        short8 vv = *(const short8*)&lds2[(hh * 128 + d) * 256 + half * 64 + kv0];
        size_t tb = ((size_t)(bb * 4 + kvh) * 32 + kt0 + half) * 8192;
        *(short8*)(vbuf + tb + d * 64 + (kv0 ^ cxor)) = vv;
      }
    }
  }
}

// --------------------------------------------------------------- AO GEMM
// 256M x 128N tiles -> grid (16,16) = 256 blocks = 100% CU coverage.
__global__ __launch_bounds__(512, 2) void gemm_bt_f32_kernel(
    const __hip_bfloat16* __restrict__ A,
    const __hip_bfloat16* __restrict__ Bt,
    float* __restrict__ C, int N, int K) {
  __shared__ __align__(16) __hip_bfloat16 lds[49152];  // 96 KiB
  const int tid = threadIdx.x;
  const int m0 = blockIdx.y * 256, n0 = blockIdx.x * 128;

  floatx4 acc[4][4] = {};
  gemm_256x128_core(A + (size_t)m0 * K, Bt + (size_t)n0 * K, K, lds, acc);

  const int wave = tid >> 6, lane = tid & 63;
  const int quad = lane >> 4, l15 = lane & 15;
  const int wm = wave >> 1, wn = wave & 1;
#pragma unroll
  for (int mi = 0; mi < 4; ++mi)
#pragma unroll
    for (int ni = 0; ni < 4; ++ni)
#pragma unroll
      for (int r = 0; r < 4; ++r) {
        int row = m0 + wm * 64 + mi * 16 + quad * 4 + r;
        int col = n0 + wn * 64 + ni * 16 + l15;
        C[(size_t)row * N + col] = acc[mi][ni][r];
      }
}

// ---------------------------------------------------------------- attention
// grid (16, 32), 256 thr. Block = 128 q-rows (2 rowsets of 64) x one head.
// SWAPPED QK^T: sc = mfma(K, Q) -> S[kv = ni*16+quad*4+r][q = l15].
// Softmax fully in-register per lane (q = l15): in-lane 15-fmax + 2 shfl_xor
// row max; per-lane scalar m/alpha/l; defer-max skips o-rescale; P reaches
// the PV A-fragment via quad-exchange ds_bpermutes (no P LDS).
__global__ __launch_bounds__(256, 2) void attn_kernel(
    const __hip_bfloat16* __restrict__ qbuf,   // [4096][2048]
    const __hip_bfloat16* __restrict__ kbuf,   // tiles
    const __hip_bfloat16* __restrict__ vbuf,   // tiles
    __hip_bfloat16* __restrict__ aout) {       // [4096][2048]
  const int qt = (blockIdx.y & 16) ? blockIdx.x : (15 - blockIdx.x);
  const int bh = blockIdx.y;
  const int b = bh >> 4, h = bh & 15;
  const int kvh = h >> 2;

  __shared__ __align__(16) __hip_bfloat16 Kbuf[2][8192];      // 2 x 16 KB
  __shared__ __align__(16) __hip_bfloat16 Vbuf[2][8192];      // 2 x 16 KB

  const int tid = threadIdx.x;
  const int wave = tid >> 6, lane = tid & 63;
  const int quad = lane >> 4, l15 = lane & 15;

  short8 qfrag[2][4];
#pragma unroll
  for (int rs = 0; rs < 2; ++rs)
#pragma unroll
    for (int kc = 0; kc < 4; ++kc)
      qfrag[rs][kc] = *(const short8*)(qbuf +
          (size_t)(b * S_LEN + qt * 128 + rs * 64 + wave * 16 + l15) * 2048 +
          h * 128 + kc * 32 + quad * 8);

  const __hip_bfloat16* ktiles = kbuf + (size_t)(b * 4 + kvh) * 32 * 8192;
  const __hip_bfloat16* vtiles = vbuf + (size_t)(b * 4 + kvh) * 32 * 8192;
  const int nt = 2 * qt + 2;

#pragma unroll
  for (int j = 0; j < 4; ++j) {
    int c = tid + 256 * j;
    gl_lds16(ktiles + c * 8, &Kbuf[0][c * 8]);
    gl_lds16(vtiles + c * 8, &Vbuf[0][c * 8]);
  }

  float m_s[2] = {-1e30f, -1e30f};
  float l_s[2] = {0.f, 0.f};
  floatx4 o[2][8] = {};

  for (int kt = 0; kt < nt; ++kt) {
    const int cur = kt & 1;
    __syncthreads();   // K(kt)/V(kt) DMA drained & visible

    if (kt + 1 < nt) {
      const __hip_bfloat16* kb = ktiles + (size_t)(kt + 1) * 8192;
      const __hip_bfloat16* vb = vtiles + (size_t)(kt + 1) * 8192;
#pragma unroll
      for (int j = 0; j < 4; ++j) {
        int c = tid + 256 * j;
        gl_lds16(kb + c * 8, &Kbuf[1 - cur][c * 8]);
        gl_lds16(vb + c * 8, &Vbuf[1 - cur][c * 8]);
      }
    }

    // S' = K Q^T (swapped): sc[rs][ni][r] = S[kv=kt*64+ni*16+quad*4+r][q=l15]
    floatx4 sc[2][4] = {};
#pragma unroll
    for (int ni = 0; ni < 4; ++ni)
#pragma unroll
      for (int kc = 0; kc < 4; ++kc) {
        short8 bf = *(const short8*)&Kbuf[cur][((kc * 4 + quad) * 64 + ni * 16 + l15) * 8];
        sc[0][ni] = __builtin_amdgcn_mfma_f32_16x16x32_bf16(bf, qfrag[0][kc], sc[0][ni], 0, 0, 0);
        sc[1][ni] = __builtin_amdgcn_mfma_f32_16x16x32_bf16(bf, qfrag[1][kc], sc[1][ni], 0, 0, 0);
      }

    short8 pa[2][2];
#pragma unroll
    for (int rs = 0; rs < 2; ++rs) {
      const int qt64 = 2 * qt + rs;
      if (kt >= qt64) {   // diagonal or beyond: causal mask
        const int qg = qt * 128 + rs * 64 + wave * 16 + l15;
#pragma unroll
        for (int ni = 0; ni < 4; ++ni) {
          int kvb = kt * 64 + ni * 16 + quad * 4;
#pragma unroll
          for (int r = 0; r < 4; ++r)
            if (kvb + r > qg) sc[rs][ni][r] = -1e30f;
        }
      }

      // per-lane row max over this tile's 64 kv
      float v = sc[rs][0][0];
#pragma unroll
      for (int ni = 0; ni < 4; ++ni)
#pragma unroll
        for (int r = 0; r < 4; ++r) v = fmaxf(v, sc[rs][ni][r]);
      v = fmaxf(v, __shfl_xor(v, 16));
      v = fmaxf(v, __shfl_xor(v, 32));

      float mold = m_s[rs];
      if (__any(v > mold + THRR)) {      // defer-max: rescale only when needed
        float mnew = fmaxf(mold, v);
        float alpha = exp2f((mold - mnew) * CP);
        m_s[rs] = mnew;
        l_s[rs] *= alpha;
        float ar[4];
#pragma unroll
        for (int r = 0; r < 4; ++r)
          ar[r] = __shfl(alpha, (lane & 48) + quad * 4 + r);
#pragma unroll
        for (int nc = 0; nc < 8; ++nc)
#pragma unroll
          for (int r = 0; r < 4; ++r) o[rs][nc][r] *= ar[r];
      }

      float mc = m_s[rs] * CP;
      unsigned pk[4][2];
      float lsum = 0.f;
#pragma unroll
      for (int ni = 0; ni < 4; ++ni)
#pragma unroll
        for (int pr = 0; pr < 2; ++pr) {
          float p0 = exp2f(sc[rs][ni][2 * pr] * CP - mc);
          float p1 = exp2f(sc[rs][ni][2 * pr + 1] * CP - mc);
          lsum += p0 + p1;
          union { unsigned u; ushort us[2]; } uu;
          union { __hip_bfloat16 h; ushort us; } b0, b1;
          b0.h = __float2bfloat16(p0); b1.h = __float2bfloat16(p1);
          uu.us[0] = b0.us; uu.us[1] = b1.us;
          pk[ni][pr] = uu.u;
        }
      lsum += __shfl_xor(lsum, 16);
      lsum += __shfl_xor(lsum, 32);
      l_s[rs] += lsum;

      // quad-redistribution: pk[ni][pr]@lane(qs,l15) -> A-frag P[q=l15][kv]
#pragma unroll
      for (int kk2 = 0; kk2 < 2; ++kk2) {
        union { unsigned w[4]; short8 s; } pw_;
#pragma unroll
        for (int j = 0; j < 4; ++j) {
          int src = ((((quad & 1) * 2) + (j >> 1)) << 4) | l15;
          unsigned lo = (unsigned)__shfl((int)pk[2 * kk2][j & 1], src);
          unsigned hi = (unsigned)__shfl((int)pk[2 * kk2 + 1][j & 1], src);
          pw_.w[j] = (quad >> 1) ? hi : lo;
        }
        pa[rs][kk2] = pw_.s;
      }
    }

    // fused PV: each V fragment loaded once, used by both rowsets
#pragma unroll
    for (int kk2 = 0; kk2 < 2; ++kk2) {
#pragma unroll
      for (int nc = 0; nc < 8; ++nc) {
        int d = nc * 16 + l15;
        int swcol = (kk2 * 32 + quad * 8) ^ ((d & 7) << 3);
        short8 vv = *(const short8*)&Vbuf[cur][d * 64 + swcol];
        o[0][nc] = __builtin_amdgcn_mfma_f32_16x16x32_bf16(pa[0][kk2], vv, o[0][nc], 0, 0, 0);
        o[1][nc] = __builtin_amdgcn_mfma_f32_16x16x32_bf16(pa[1][kk2], vv, o[1][nc], 0, 0, 0);
      }
    }
  }

#pragma unroll
  for (int rs = 0; rs < 2; ++rs) {
    float inv[4];
#pragma unroll
    for (int r = 0; r < 4; ++r) {
      float lr = __shfl(l_s[rs], (lane & 48) + quad * 4 + r);
      inv[r] = 1.0f / lr;
    }
    const size_t orow0 = (size_t)(b * S_LEN + qt * 128 + rs * 64 + wave * 16 + quad * 4);
#pragma unroll
    for (int nc = 0; nc < 8; ++nc)
#pragma unroll
      for (int r = 0; r < 4; ++r)
        aout[(orow0 + r) * 2048 + h * 128 + nc * 16 + l15] =
            __float2bfloat16(o[rs][nc][r] * inv[r]);
  }
}

// -------------------------------------------------------------------- launch
extern "C" void kernel_launch(void* const* d_in, const int* in_sizes, int n_in,
                              void* d_out, int out_size, void* d_ws, size_t ws_size,
                              hipStream_t stream) {
  const float* x    = (const float*)d_in[0];
  const float* cosb = (const float*)d_in[1];
  const float* sinb = (const float*)d_in[2];
  // d_in[3] = mask (causal, analytic)
  const float* Wq = (const float*)d_in[4];
  const float* Wk = (const float*)d_in[5];
  const float* Wv = (const float*)d_in[6];
  const float* Wo = (const float*)d_in[7];
  float* out = (float*)d_out;

  char* ws = (char*)d_ws;
  __hip_bfloat16* xb    = (__hip_bfloat16*)(ws);                 // 16 MB
  __hip_bfloat16* wqkvt = (__hip_bfloat16*)(ws + (16u << 20));   // 12 MB [3072][2048]
  __hip_bfloat16* wot   = (__hip_bfloat16*)(ws + (28u << 20));   // 8 MB  [2048][2048]
  __hip_bfloat16* qbuf  = (__hip_bfloat16*)(ws + (36u << 20));   // 16 MB [4096][2048]
  __hip_bfloat16* kbuf  = (__hip_bfloat16*)(ws + (52u << 20));   // 4 MB  tiles
  __hip_bfloat16* vbuf  = (__hip_bfloat16*)(ws + (56u << 20));   // 4 MB  tiles
  __hip_bfloat16* aout  = (__hip_bfloat16*)(ws + (60u << 20));   // 16 MB [4096][2048]

  prep_kernel<<<18432, 256, 0, stream>>>(x, Wq, Wk, Wv, Wo, xb, wqkvt, wot);
  qkv_gemm_kernel<<<dim3(12, 16), 512, 0, stream>>>(xb, wqkvt, qbuf, kbuf, vbuf, cosb, sinb);
  attn_kernel<<<dim3(16, 32), 256, 0, stream>>>(qbuf, kbuf, vbuf, aout);
  gemm_bt_f32_kernel<<<dim3(16, 16), 512, 0, stream>>>(aout, wot, out, 2048, 2048);
}